// Round 4
// baseline (563.075 us; speedup 1.0000x reference)
//
#include <hip/hip_runtime.h>

#define NN 200000
#define NE 600000
#define NG 1024
#define HH 512

typedef short short8 __attribute__((ext_vector_type(8)));
typedef float f32x4 __attribute__((ext_vector_type(4)));

__device__ __forceinline__ unsigned short f2bf(float f){
  unsigned u = __float_as_uint(f);
  u += 0x7fffu + ((u >> 16) & 1u);
  return (unsigned short)(u >> 16);
}

// gelu(x) = x * sigmoid(1.5957691216*x + 0.07135481627*x^3)  (tanh-form GELU)
__device__ __forceinline__ float gelu_f(float x){
  float p = __builtin_fmaf(x*x, -0.10294325f, -2.3022085f);
  float e = __builtin_amdgcn_exp2f(x * p);
  return x * __builtin_amdgcn_rcpf(1.0f + e);
}

// ========== merged: kprep (196 blk) + kbound (782 blk) + khist_edge (256 blk) ==========
__global__ __launch_bounds__(256) void kpre(
    const float* __restrict__ nfw1, const float* __restrict__ nfb1,
    const float* __restrict__ nfg1, const float* __restrict__ nfbe1,
    const float* __restrict__ efw1, const float* __restrict__ efb1,
    const float* __restrict__ efg1, const float* __restrict__ efbe1,
    unsigned short* __restrict__ w1nT, unsigned short* __restrict__ w1eT,
    float* __restrict__ b1n, float* __restrict__ b1e,
    const int* __restrict__ bidx, int* __restrict__ nstart,
    const int* __restrict__ eidx, int* __restrict__ eg, int* __restrict__ cnte){
  __shared__ int h[NG];
  const float rs = 0.99999500003750f;   // 1/sqrt(1+1e-5)
  int b = blockIdx.x, t = threadIdx.x;
  if (b < 196){
    int tid = b*256 + t;
    if (tid < 512*64){
      int c = tid >> 6, k = tid & 63;
      float w = (k < 41) ? nfw1[k*HH + c] * nfg1[c] * rs : 0.0f;
      w1nT[tid] = f2bf(w);
    } else if (tid < 512*96){
      int u = tid - 512*64; int c = u >> 5, k = u & 31;
      float w = (k < 16) ? efw1[k*HH + c] * efg1[c] * rs : 0.0f;
      w1eT[u] = f2bf(w);
    } else if (tid < 512*96 + 512){
      int c = tid - 512*96;
      b1n[c] = nfb1[c]*nfg1[c]*rs + nfbe1[c];
    } else if (tid < 512*96 + 1024){
      int c = tid - (512*96 + 512);
      b1e[c] = efb1[c]*efg1[c]*rs + efbe1[c];
    }
  } else if (b < 196 + 782){
    int i = (b-196)*256 + t;
    if (i < NN){
      int g0 = bidx[i];
      int g1 = (i+1 < NN) ? bidx[i+1] : NG;
      for (int g = g0+1; g <= g1; ++g) nstart[g] = i+1;
      if (i == 0) for (int g = 0; g <= g0; ++g) nstart[g] = 0;
    }
  } else {
    int hb = b - (196 + 782);             // 0..255
    for (int u = t; u < NG; u += 256) h[u] = 0;
    __syncthreads();
    for (int e = hb*256 + t; e < NE; e += 256*256){
      int g = bidx[eidx[e]];
      eg[e] = g;
      atomicAdd(&h[g], 1);
    }
    __syncthreads();
    for (int u = t; u < NG; u += 256){ int c = h[u]; if (c) atomicAdd(&cnte[u], c); }
  }
}

// ========== merged: kscan (block 0) + kinit (blocks 1..128) ==========
__global__ __launch_bounds__(1024) void kscan_init(const int* __restrict__ cnte, int* __restrict__ cursor,
    const float* __restrict__ gf, const int* __restrict__ nstart,
    const float* __restrict__ b2n, const float* __restrict__ b2e,
    const float* __restrict__ ob1, const float* __restrict__ ob2,
    float* __restrict__ gh, float* __restrict__ y1, float* __restrict__ y2){
  if (blockIdx.x == 0){
    __shared__ int s[NG];
    int t = threadIdx.x;
    int v = cnte[t]; s[t] = v; __syncthreads();
    for (int d = 1; d < NG; d <<= 1){
      int x = (t >= d) ? s[t-d] : 0;
      __syncthreads();
      s[t] += x;
      __syncthreads();
    }
    cursor[t] = s[t] - v;
  } else {
    int i = (blockIdx.x - 1)*1024 + threadIdx.x;   // float4 index over 1024*512/4
    int f = i*4;
    int r = f >> 9, c = f & 511;
    float cn = (float)(nstart[r+1] - nstart[r]);
    float ce = (float)cnte[r];
    float4 gv = *(const float4*)&gf[f];
    float4 bn4 = *(const float4*)&b2n[c];
    float4 be4 = *(const float4*)&b2e[c];
    float4 o;
    o.x = gv.x + cn*bn4.x + ce*be4.x;
    o.y = gv.y + cn*bn4.y + ce*be4.y;
    o.z = gv.z + cn*bn4.z + ce*be4.z;
    o.w = gv.w + cn*bn4.w + ce*be4.w;
    *(float4*)&gh[f] = o;
    *(float4*)&y1[f] = *(const float4*)&ob1[c];
    *(float4*)&y2[f] = *(const float4*)&ob2[c];
  }
}

// ========== counting-sort scatter ==========
__global__ __launch_bounds__(1024) void kscatter(const int* __restrict__ eg, int* __restrict__ cursor,
                                                 int* __restrict__ perm, int* __restrict__ sg){
  __shared__ int h[NG], base[NG];
  const int per = (NE + gridDim.x - 1) / gridDim.x;
  const int lo = blockIdx.x * per, hi = min(lo + per, NE);
  for (int t = threadIdx.x; t < NG; t += 1024) h[t] = 0;
  __syncthreads();
  for (int e = lo + threadIdx.x; e < hi; e += 1024) atomicAdd(&h[eg[e]], 1);
  __syncthreads();
  for (int t = threadIdx.x; t < NG; t += 1024){
    int c = h[t];
    base[t] = c ? atomicAdd(&cursor[t], c) : 0;
    h[t] = 0;
  }
  __syncthreads();
  for (int e = lo + threadIdx.x; e < hi; e += 1024){
    int g = eg[e];
    int p = base[g] + atomicAdd(&h[g], 1);
    perm[p] = e; sg[p] = g;
  }
}

// ---- shared reduction macro: wok wave-sum / tok tile-sum / boundary two-graph ----
#define SEG_REDUCE(Sbase, CB, v0, v1, v2, v3, rt, wsum)                                    \
  do {                                                                                     \
    if (wok){                                                                              \
      wsum += (v0+v1)+(v2+v3);                                                             \
    } else if (tok[rt]){                                                                   \
      float ts = (v0+v1)+(v2+v3);                                                          \
      ts += __shfl_xor(ts, 16);                                                            \
      ts += __shfl_xor(ts, 32);                                                            \
      if (lane < 16) unsafeAtomicAdd(&Sbase[(size_t)gfi[rt]*1024 + (CB) + lane], ts);      \
    } else {                                                                               \
      int gA = gfi[rt], gB = gla[rt];                                                      \
      float sA = 0.f, sB = 0.f;                                                            \
      sA += (g4[rt].x==gA)?v0:0.f; sB += (g4[rt].x==gB)?v0:0.f;                            \
      sA += (g4[rt].y==gA)?v1:0.f; sB += (g4[rt].y==gB)?v1:0.f;                            \
      sA += (g4[rt].z==gA)?v2:0.f; sB += (g4[rt].z==gB)?v2:0.f;                            \
      sA += (g4[rt].w==gA)?v3:0.f; sB += (g4[rt].w==gB)?v3:0.f;                            \
      int cb = (CB) + m;                                                                   \
      if (g4[rt].x>=0 && g4[rt].x!=gA && g4[rt].x!=gB) unsafeAtomicAdd(&Sbase[(size_t)g4[rt].x*1024 + cb], v0); \
      if (g4[rt].y>=0 && g4[rt].y!=gA && g4[rt].y!=gB) unsafeAtomicAdd(&Sbase[(size_t)g4[rt].y*1024 + cb], v1); \
      if (g4[rt].z>=0 && g4[rt].z!=gA && g4[rt].z!=gB) unsafeAtomicAdd(&Sbase[(size_t)g4[rt].z*1024 + cb], v2); \
      if (g4[rt].w>=0 && g4[rt].w!=gA && g4[rt].w!=gB) unsafeAtomicAdd(&Sbase[(size_t)g4[rt].w*1024 + cb], v3); \
      sA += __shfl_xor(sA, 16); sA += __shfl_xor(sA, 32);                                  \
      sB += __shfl_xor(sB, 16); sB += __shfl_xor(sB, 32);                                  \
      if (lane < 16){                                                                      \
        unsafeAtomicAdd(&Sbase[(size_t)gA*1024 + (CB) + lane], sA);                        \
        unsafeAtomicAdd(&Sbase[(size_t)gB*1024 + (CB) + lane], sB);                        \
      }                                                                                    \
    }                                                                                      \
  } while(0)

#define WOK_FLUSH(Sbase, CB, wsum)                                                         \
  do { if (wok){                                                                           \
    wsum += __shfl_xor(wsum, 16);                                                          \
    wsum += __shfl_xor(wsum, 32);                                                          \
    if (lane < 16) unsafeAtomicAdd(&Sbase[(size_t)gW*1024 + (CB) + lane], wsum);           \
  } } while(0)

// ========== node first layer: rt=4, prefetch, bias-in-C ==========
__global__ __launch_bounds__(256) void knode(const float* __restrict__ nf, const float* __restrict__ dp,
    const int* __restrict__ ny, const int* __restrict__ bidx,
    const unsigned short* __restrict__ w1nT, const float* __restrict__ b1n, float* __restrict__ S){
  const int lane = threadIdx.x & 63, wv = threadIdx.x >> 6;
  const int q = lane >> 4, m = lane & 15;
  const int r0 = blockIdx.x*256 + wv*64;
  short8 a0[4], a1[4];
  int4 g4[4];
  int gfi[4], gla[4]; bool tok[4];
  const short8 zz = {0,0,0,0,0,0,0,0};
#pragma unroll
  for (int rt=0; rt<4; ++rt){
    int rb = r0 + rt*16;
    int row = rb + m;
    bool valid = row < NN;
    int ar = valid ? row : (NN-1);
    const float4* ap = (const float4*)(nf + (size_t)ar*32 + q*8);
    float4 xa = ap[0], xb = ap[1];
    short8 f;
    f[0]=(short)f2bf(xa.x); f[1]=(short)f2bf(xa.y); f[2]=(short)f2bf(xa.z); f[3]=(short)f2bf(xa.w);
    f[4]=(short)f2bf(xb.x); f[5]=(short)f2bf(xb.y); f[6]=(short)f2bf(xb.z); f[7]=(short)f2bf(xb.w);
    if (!valid) f = zz;
    a0[rt] = f;
    int cls = ny[ar];
    short dpb = (short)f2bf(dp[ar]);
    short8 h = zz;
    if (valid){
      if (q == 0){
#pragma unroll
        for (int j=0;j<8;++j) h[j] = (cls==j) ? dpb : (short)0;
      } else if (q == 1 && cls == 8) h[0] = dpb;
    }
    a1[rt] = h;
    int gb = rb + q*4;
    if (gb + 3 < NN) g4[rt] = *(const int4*)(bidx + gb);
    else {
      g4[rt].x = (gb   < NN) ? bidx[gb  ] : -1;
      g4[rt].y = (gb+1 < NN) ? bidx[gb+1] : -1;
      g4[rt].z = (gb+2 < NN) ? bidx[gb+2] : -1;
      g4[rt].w = (gb+3 < NN) ? bidx[gb+3] : -1;
    }
    int gA = bidx[min(rb, NN-1)], gB = bidx[min(rb+15, NN-1)];
    tok[rt] = (rb + 15 < NN) && (gA == gB);
    gfi[rt] = gA; gla[rt] = gB;
  }
  int gW = bidx[min(r0, NN-1)];
  bool wok = (r0 + 63 < NN) && (gW == bidx[min(r0+63, NN-1)]);

  const short8* bp0 = (const short8*)(w1nT + (m << 6) + (q << 3));
  short8 b0 = bp0[0], b1 = bp0[4];
  float bias = b1n[m];

  for (int nt=0; nt<32; ++nt){
    int ntn = (nt + 1) & 31;
    const short8* np = (const short8*)(w1nT + (((ntn<<4) + m) << 6) + (q << 3));
    short8 pb0 = np[0], pb1 = np[4];
    float pbias = b1n[(ntn<<4) + m];
    float wsum = 0.0f;
    const int CB = nt<<4;
#pragma unroll
    for (int rt=0; rt<4; ++rt){
      f32x4 acc = {bias, bias, bias, bias};
      acc = __builtin_amdgcn_mfma_f32_16x16x32_bf16(a0[rt], b0, acc, 0, 0, 0);
      acc = __builtin_amdgcn_mfma_f32_16x16x32_bf16(a1[rt], b1, acc, 0, 0, 0);
      float v0 = gelu_f(acc[0]);
      float v1 = gelu_f(acc[1]);
      float v2 = gelu_f(acc[2]);
      float v3 = gelu_f(acc[3]);
      SEG_REDUCE(S, CB, v0, v1, v2, v3, rt, wsum);
    }
    WOK_FLUSH(S, CB, wsum);
    b0 = pb0; b1 = pb1; bias = pbias;
  }
}

// ========== edge first layer: rt=4, ct=2 (32 cols/iter), prefetch, bias-in-C ==========
__global__ __launch_bounds__(256) void kedge(const float* __restrict__ ef, const int* __restrict__ perm,
    const int* __restrict__ sg, const unsigned short* __restrict__ w1eT, const float* __restrict__ b1e,
    float* __restrict__ Se){
  const int lane = threadIdx.x & 63, wv = threadIdx.x >> 6;
  const int q = lane >> 4, m = lane & 15;
  const int r0 = blockIdx.x*256 + wv*64;
  short8 a0[4];
  int4 g4[4];
  int gfi[4], gla[4]; bool tok[4];
  const short8 zz = {0,0,0,0,0,0,0,0};
#pragma unroll
  for (int rt=0; rt<4; ++rt){
    int rb = r0 + rt*16;
    int row = rb + m;
    bool valid = row < NE;
    int e = perm[valid ? row : (NE-1)];
    short8 f = zz;
    if (valid && q < 2){
      const float4* ap = (const float4*)(ef + (size_t)e*16 + q*8);
      float4 xa = ap[0], xb = ap[1];
      f[0]=(short)f2bf(xa.x); f[1]=(short)f2bf(xa.y); f[2]=(short)f2bf(xa.z); f[3]=(short)f2bf(xa.w);
      f[4]=(short)f2bf(xb.x); f[5]=(short)f2bf(xb.y); f[6]=(short)f2bf(xb.z); f[7]=(short)f2bf(xb.w);
    }
    a0[rt] = f;
    int gb = rb + q*4;
    if (gb + 3 < NE) g4[rt] = *(const int4*)(sg + gb);
    else {
      g4[rt].x = (gb   < NE) ? sg[gb  ] : -1;
      g4[rt].y = (gb+1 < NE) ? sg[gb+1] : -1;
      g4[rt].z = (gb+2 < NE) ? sg[gb+2] : -1;
      g4[rt].w = (gb+3 < NE) ? sg[gb+3] : -1;
    }
    int gA = sg[min(rb, NE-1)], gB = sg[min(rb+15, NE-1)];
    tok[rt] = (rb + 15 < NE) && (gA == gB);
    gfi[rt] = gA; gla[rt] = gB;
  }
  int gW = sg[min(r0, NE-1)];
  bool wok = (r0 + 63 < NE) && (gW == sg[min(r0+63, NE-1)]);

  const short8* f0 = (const short8*)(w1eT + (m << 5) + (q << 3));
  const short8* f1 = (const short8*)(w1eT + ((16 + m) << 5) + (q << 3));
  short8 b0 = f0[0], b1 = f1[0];
  float bi0 = b1e[m], bi1 = b1e[16 + m];

  for (int it=0; it<16; ++it){
    int itn = (it + 1) & 15;
    const short8* n0 = (const short8*)(w1eT + (((itn<<5) + m) << 5) + (q << 3));
    const short8* n1 = (const short8*)(w1eT + (((itn<<5) + 16 + m) << 5) + (q << 3));
    short8 p0 = n0[0], p1 = n1[0];
    float pb0 = b1e[(itn<<5) + m], pb1 = b1e[(itn<<5) + 16 + m];
    {
      const int CB = it<<5;
      float wsum = 0.0f;
#pragma unroll
      for (int rt=0; rt<4; ++rt){
        f32x4 acc = {bi0, bi0, bi0, bi0};
        acc = __builtin_amdgcn_mfma_f32_16x16x32_bf16(a0[rt], b0, acc, 0, 0, 0);
        float v0 = gelu_f(acc[0]);
        float v1 = gelu_f(acc[1]);
        float v2 = gelu_f(acc[2]);
        float v3 = gelu_f(acc[3]);
        SEG_REDUCE(Se, CB, v0, v1, v2, v3, rt, wsum);
      }
      WOK_FLUSH(Se, CB, wsum);
    }
    {
      const int CB = (it<<5) + 16;
      float wsum = 0.0f;
#pragma unroll
      for (int rt=0; rt<4; ++rt){
        f32x4 acc = {bi1, bi1, bi1, bi1};
        acc = __builtin_amdgcn_mfma_f32_16x16x32_bf16(a0[rt], b1, acc, 0, 0, 0);
        float v0 = gelu_f(acc[0]);
        float v1 = gelu_f(acc[1]);
        float v2 = gelu_f(acc[2]);
        float v3 = gelu_f(acc[3]);
        SEG_REDUCE(Se, CB, v0, v1, v2, v3, rt, wsum);
      }
      WOK_FLUSH(Se, CB, wsum);
    }
    b0 = p0; b1 = p1; bi0 = pb0; bi1 = pb1;
  }
}

// ========== split-K fp32 GEMM, atomic accumulate; optional gelu(bn()) on A ==========
__global__ __launch_bounds__(256) void kgemm_sk(const float* __restrict__ A, int lda,
    const float* __restrict__ B0, const float* __restrict__ B1, float* __restrict__ out,
    int act, const float* __restrict__ gam, const float* __restrict__ bet){
  __shared__ float Ast[16*68];
  __shared__ float Bs[16*68];
  const int t = threadIdx.x, tx = t & 15, ty = t >> 4;
  const int c0 = blockIdx.x*64, r0 = blockIdx.y*64, kbase = blockIdx.z*256;
  const float rs = 0.99999500003750f;
  float acc[4][4] = {};
  for (int ks=0; ks<16; ++ks){
    const int k0 = kbase + ks*16;
    const float* Bp = (k0 < HH) ? (B0 + (size_t)k0*HH) : (B1 + (size_t)(k0-HH)*HH);
#pragma unroll
    for (int u=0; u<4; ++u){
      int ff = t + u*256;
      int ak = k0 + (ff & 15);
      float av = A[(size_t)(r0 + (ff >> 4))*lda + ak];
      if (act) av = gelu_f(av * (gam[ak]*rs) + bet[ak]);
      Ast[(ff & 15)*68 + (ff >> 4)] = av;
      Bs[(ff >> 6)*68 + (ff & 63)] = Bp[(size_t)(ff >> 6)*HH + c0 + (ff & 63)];
    }
    __syncthreads();
#pragma unroll
    for (int k=0;k<16;++k){
      float4 a4 = *(const float4*)&Ast[k*68 + ty*4];
      float4 b4 = *(const float4*)&Bs[k*68 + tx*4];
      float av[4] = {a4.x, a4.y, a4.z, a4.w};
      float bv[4] = {b4.x, b4.y, b4.z, b4.w};
#pragma unroll
      for (int i=0;i<4;++i)
#pragma unroll
        for (int j=0;j<4;++j) acc[i][j] = __builtin_fmaf(av[i], bv[j], acc[i][j]);
    }
    __syncthreads();
  }
  const int r = r0 + ty*4, c = c0 + tx*4;
#pragma unroll
  for (int i=0;i<4;++i)
#pragma unroll
    for (int j=0;j<4;++j) unsafeAtomicAdd(&out[(size_t)(r+i)*HH + c + j], acc[i][j]);
}

// ========== final: x2 = gelu(bn(y2)); out = x2@ow3 + ob3 ==========
__global__ __launch_bounds__(256) void kfinal(const float* __restrict__ y2, const float* __restrict__ og2,
    const float* __restrict__ obe2, const float* __restrict__ w3, const float* __restrict__ b3,
    float* __restrict__ out){
  const float rs = 0.99999500003750f;
  const int lane = threadIdx.x & 63, wv = threadIdx.x >> 6;
  const int r = blockIdx.x*4 + wv;
  float a0 = 0.f, a1 = 0.f;
#pragma unroll
  for (int tt=0; tt<8; ++tt){
    int k = lane + tt*64;
    float x = gelu_f(y2[(size_t)r*HH + k] * (og2[k]*rs) + obe2[k]);
    a0 = __builtin_fmaf(x, w3[2*k], a0);
    a1 = __builtin_fmaf(x, w3[2*k+1], a1);
  }
#pragma unroll
  for (int d=1; d<64; d<<=1){ a0 += __shfl_xor(a0, d); a1 += __shfl_xor(a1, d); }
  if (lane == 0){ out[r*2] = a0 + b3[0]; out[r*2+1] = a1 + b3[1]; }
}

extern "C" void kernel_launch(void* const* d_in, const int* in_sizes, int n_in,
                              void* d_out, int out_size, void* d_ws, size_t ws_size,
                              hipStream_t stream) {
  const float* nf    = (const float*)d_in[0];
  const float* ef    = (const float*)d_in[1];
  const float* gf    = (const float*)d_in[2];
  const float* dp    = (const float*)d_in[3];
  const int*   ny    = (const int*)d_in[4];
  const int*   bidx  = (const int*)d_in[5];
  const int*   eidx  = (const int*)d_in[6];
  const float* nfw1  = (const float*)d_in[7];
  const float* nfb1  = (const float*)d_in[8];
  const float* nfg1  = (const float*)d_in[9];
  const float* nfbe1 = (const float*)d_in[10];
  const float* w2n   = (const float*)d_in[11];
  const float* b2n   = (const float*)d_in[12];
  const float* efw1  = (const float*)d_in[13];
  const float* efb1  = (const float*)d_in[14];
  const float* efg1  = (const float*)d_in[15];
  const float* efbe1 = (const float*)d_in[16];
  const float* w2e   = (const float*)d_in[17];
  const float* b2e   = (const float*)d_in[18];
  const float* ow1   = (const float*)d_in[19];
  const float* ob1   = (const float*)d_in[20];
  const float* og1   = (const float*)d_in[21];
  const float* obe1  = (const float*)d_in[22];
  const float* ow2   = (const float*)d_in[23];
  const float* ob2   = (const float*)d_in[24];
  const float* og2   = (const float*)d_in[25];
  const float* obe2  = (const float*)d_in[26];
  const float* ow3   = (const float*)d_in[27];
  const float* ob3   = (const float*)d_in[28];

  float* S    = (float*)d_ws;                 // 1024 x 1024 (node cols 0-511, edge cols 512-1023)
  int* cnte   = (int*)(S + NG*1024);          // 1024
  int* cursor = cnte + NG;                    // 1024
  int* nstart = cursor + NG;                  // 1025
  int* eg     = nstart + NG + 1;              // NE
  int* perm   = eg + NE;                      // NE
  int* sg     = perm + NE;                    // NE
  unsigned short* w1nT = (unsigned short*)(sg + NE);  // 512*64
  unsigned short* w1eT = w1nT + HH*64;                // 512*32
  float* b1n  = (float*)(w1eT + HH*32);       // 512
  float* b1e  = b1n + HH;                     // 512
  float* gh   = b1e + HH;                     // 1024*512
  float* y1   = gh + NG*HH;                   // 1024*512
  float* y2   = y1 + NG*HH;                   // 1024*512

  hipMemsetAsync(d_ws, 0, (size_t)NG*1024*sizeof(float) + NG*sizeof(int), stream);

  kpre<<<196 + 782 + 256, 256, 0, stream>>>(nfw1, nfb1, nfg1, nfbe1, efw1, efb1, efg1, efbe1,
                                            w1nT, w1eT, b1n, b1e, bidx, nstart, eidx, eg, cnte);
  kscan_init<<<129, 1024, 0, stream>>>(cnte, cursor, gf, nstart, b2n, b2e, ob1, ob2, gh, y1, y2);
  kscatter<<<128, 1024, 0, stream>>>(eg, cursor, perm, sg);
  knode<<<(NN+255)/256, 256, 0, stream>>>(nf, dp, ny, bidx, w1nT, b1n, S);
  kedge<<<(NE+255)/256, 256, 0, stream>>>(ef, perm, sg, w1eT, b1e, S + 512);
  // gh += [Sn|Se] @ [W2n;W2e]   (split-K=4)
  kgemm_sk<<<dim3(8,16,4), 256, 0, stream>>>(S, 1024, w2n, w2e, gh, 0, nullptr, nullptr);
  // y1 += gh @ ow1              (split-K=2)
  kgemm_sk<<<dim3(8,16,2), 256, 0, stream>>>(gh, 512, ow1, ow1, y1, 0, nullptr, nullptr);
  // y2 += gelu(bn(y1)) @ ow2    (split-K=2, activation fused into A-staging)
  kgemm_sk<<<dim3(8,16,2), 256, 0, stream>>>(y1, 512, ow2, ow2, y2, 1, og1, obe1);
  kfinal<<<NG/4, 256, 0, stream>>>(y2, og2, obe2, ow3, ob3, (float*)d_out);
}

// Round 5
// 541.284 us; speedup vs baseline: 1.0403x; 1.0403x over previous
//
#include <hip/hip_runtime.h>

#define NN 200000
#define NE 600000
#define NG 1024
#define HH 512

typedef short short8 __attribute__((ext_vector_type(8)));
typedef float f32x4 __attribute__((ext_vector_type(4)));

__device__ __forceinline__ unsigned short f2bf(float f){
  unsigned u = __float_as_uint(f);
  u += 0x7fffu + ((u >> 16) & 1u);
  return (unsigned short)(u >> 16);
}
__device__ __forceinline__ float bf2f(unsigned short h){
  return __uint_as_float(((unsigned)h) << 16);
}

// gelu(x) = x * sigmoid(1.5957691216*x + 0.07135481627*x^3)  (tanh-form GELU)
__device__ __forceinline__ float gelu_f(float x){
  float p = __builtin_fmaf(x*x, -0.10294325f, -2.3022085f);
  float e = __builtin_amdgcn_exp2f(x * p);
  return x * __builtin_amdgcn_rcpf(1.0f + e);
}

// ========== merged: kprep (196 blk) + kbound (782 blk) + khist_edge (256 blk) ==========
__global__ __launch_bounds__(256) void kpre(
    const float* __restrict__ nfw1, const float* __restrict__ nfb1,
    const float* __restrict__ nfg1, const float* __restrict__ nfbe1,
    const float* __restrict__ efw1, const float* __restrict__ efb1,
    const float* __restrict__ efg1, const float* __restrict__ efbe1,
    unsigned short* __restrict__ w1nT, unsigned short* __restrict__ w1eT,
    float* __restrict__ b1n, float* __restrict__ b1e,
    const int* __restrict__ bidx, int* __restrict__ nstart,
    const int* __restrict__ eidx, int* __restrict__ eg, int* __restrict__ cnte){
  __shared__ int h[NG];
  const float rs = 0.99999500003750f;   // 1/sqrt(1+1e-5)
  int b = blockIdx.x, t = threadIdx.x;
  if (b < 196){
    int tid = b*256 + t;
    if (tid < 512*64){
      int c = tid >> 6, k = tid & 63;
      float w = (k < 41) ? nfw1[k*HH + c] * nfg1[c] * rs : 0.0f;
      w1nT[tid] = f2bf(w);
    } else if (tid < 512*96){
      int u = tid - 512*64; int c = u >> 5, k = u & 31;
      float w = (k < 16) ? efw1[k*HH + c] * efg1[c] * rs : 0.0f;
      w1eT[u] = f2bf(w);
    } else if (tid < 512*96 + 512){
      int c = tid - 512*96;
      b1n[c] = nfb1[c]*nfg1[c]*rs + nfbe1[c];
    } else if (tid < 512*96 + 1024){
      int c = tid - (512*96 + 512);
      b1e[c] = efb1[c]*efg1[c]*rs + efbe1[c];
    }
  } else if (b < 196 + 782){
    int i = (b-196)*256 + t;
    if (i < NN){
      int g0 = bidx[i];
      int g1 = (i+1 < NN) ? bidx[i+1] : NG;
      for (int g = g0+1; g <= g1; ++g) nstart[g] = i+1;
      if (i == 0) for (int g = 0; g <= g0; ++g) nstart[g] = 0;
    }
  } else {
    int hb = b - (196 + 782);             // 0..255
    for (int u = t; u < NG; u += 256) h[u] = 0;
    __syncthreads();
    for (int e = hb*256 + t; e < NE; e += 256*256){
      int g = bidx[eidx[e]];
      eg[e] = g;
      atomicAdd(&h[g], 1);
    }
    __syncthreads();
    for (int u = t; u < NG; u += 256){ int c = h[u]; if (c) atomicAdd(&cnte[u], c); }
  }
}

// ========== merged: kscan (block 0) + gh-init (blocks 1..128) ==========
__global__ __launch_bounds__(1024) void kscan_init(const int* __restrict__ cnte, int* __restrict__ cursor,
    const float* __restrict__ gf, const int* __restrict__ nstart,
    const float* __restrict__ b2n, const float* __restrict__ b2e,
    float* __restrict__ gh){
  if (blockIdx.x == 0){
    __shared__ int s[NG];
    int t = threadIdx.x;
    int v = cnte[t]; s[t] = v; __syncthreads();
    for (int d = 1; d < NG; d <<= 1){
      int x = (t >= d) ? s[t-d] : 0;
      __syncthreads();
      s[t] += x;
      __syncthreads();
    }
    cursor[t] = s[t] - v;
  } else {
    int i = (blockIdx.x - 1)*1024 + threadIdx.x;   // float4 index over 1024*512/4
    int f = i*4;
    int r = f >> 9, c = f & 511;
    float cn = (float)(nstart[r+1] - nstart[r]);
    float ce = (float)cnte[r];
    float4 gv = *(const float4*)&gf[f];
    float4 bn4 = *(const float4*)&b2n[c];
    float4 be4 = *(const float4*)&b2e[c];
    float4 o;
    o.x = gv.x + cn*bn4.x + ce*be4.x;
    o.y = gv.y + cn*bn4.y + ce*be4.y;
    o.z = gv.z + cn*bn4.z + ce*be4.z;
    o.w = gv.w + cn*bn4.w + ce*be4.w;
    *(float4*)&gh[f] = o;
  }
}

// ========== counting-sort scatter ==========
__global__ __launch_bounds__(1024) void kscatter(const int* __restrict__ eg, int* __restrict__ cursor,
                                                 int* __restrict__ perm, int* __restrict__ sg){
  __shared__ int h[NG], base[NG];
  const int per = (NE + gridDim.x - 1) / gridDim.x;
  const int lo = blockIdx.x * per, hi = min(lo + per, NE);
  for (int t = threadIdx.x; t < NG; t += 1024) h[t] = 0;
  __syncthreads();
  for (int e = lo + threadIdx.x; e < hi; e += 1024) atomicAdd(&h[eg[e]], 1);
  __syncthreads();
  for (int t = threadIdx.x; t < NG; t += 1024){
    int c = h[t];
    base[t] = c ? atomicAdd(&cursor[t], c) : 0;
    h[t] = 0;
  }
  __syncthreads();
  for (int e = lo + threadIdx.x; e < hi; e += 1024){
    int g = eg[e];
    int p = base[g] + atomicAdd(&h[g], 1);
    perm[p] = e; sg[p] = g;
  }
}

// ========== node first layer: r3 structure (rt=2, prefetch, bias-in-C) ==========
__global__ __launch_bounds__(256) void knode(const float* __restrict__ nf, const float* __restrict__ dp,
    const int* __restrict__ ny, const int* __restrict__ bidx,
    const unsigned short* __restrict__ w1nT, const float* __restrict__ b1n, float* __restrict__ S){
  const int lane = threadIdx.x & 63, wv = threadIdx.x >> 6;
  const int q = lane >> 4, m = lane & 15;
  const int r0 = blockIdx.x*128 + wv*32;
  short8 a0[2], a1[2];
  int4 g4[2];
  int gfi[2], gla[2]; bool tok[2];
  const short8 zz = {0,0,0,0,0,0,0,0};
#pragma unroll
  for (int rt=0; rt<2; ++rt){
    int rb = r0 + rt*16;
    int row = rb + m;
    bool valid = row < NN;
    int ar = valid ? row : (NN-1);
    const float4* ap = (const float4*)(nf + (size_t)ar*32 + q*8);
    float4 xa = ap[0], xb = ap[1];
    short8 f;
    f[0]=(short)f2bf(xa.x); f[1]=(short)f2bf(xa.y); f[2]=(short)f2bf(xa.z); f[3]=(short)f2bf(xa.w);
    f[4]=(short)f2bf(xb.x); f[5]=(short)f2bf(xb.y); f[6]=(short)f2bf(xb.z); f[7]=(short)f2bf(xb.w);
    if (!valid) f = zz;
    a0[rt] = f;
    int cls = ny[ar];
    short dpb = (short)f2bf(dp[ar]);
    short8 h = zz;
    if (valid){
      if (q == 0){
#pragma unroll
        for (int j=0;j<8;++j) h[j] = (cls==j) ? dpb : (short)0;
      } else if (q == 1 && cls == 8) h[0] = dpb;
    }
    a1[rt] = h;
    int gb = rb + q*4;
    if (gb + 3 < NN) g4[rt] = *(const int4*)(bidx + gb);
    else {
      g4[rt].x = (gb   < NN) ? bidx[gb  ] : -1;
      g4[rt].y = (gb+1 < NN) ? bidx[gb+1] : -1;
      g4[rt].z = (gb+2 < NN) ? bidx[gb+2] : -1;
      g4[rt].w = (gb+3 < NN) ? bidx[gb+3] : -1;
    }
    int gA = bidx[min(rb, NN-1)], gB = bidx[min(rb+15, NN-1)];
    tok[rt] = (rb + 15 < NN) && (gA == gB);
    gfi[rt] = gA; gla[rt] = gB;
  }
  int gW = bidx[min(r0, NN-1)];
  bool wok = (r0 + 31 < NN) && (gW == bidx[min(r0+31, NN-1)]);

  const short8* bp0 = (const short8*)(w1nT + (m << 6) + (q << 3));
  short8 b0 = bp0[0], b1 = bp0[4];
  float bias = b1n[m];

  for (int nt=0; nt<32; ++nt){
    int ntn = (nt + 1) & 31;
    const short8* np = (const short8*)(w1nT + (((ntn<<4) + m) << 6) + (q << 3));
    short8 pb0 = np[0], pb1 = np[4];
    float pbias = b1n[(ntn<<4) + m];
    float wsum = 0.0f;
#pragma unroll
    for (int rt=0; rt<2; ++rt){
      f32x4 acc = {bias, bias, bias, bias};
      acc = __builtin_amdgcn_mfma_f32_16x16x32_bf16(a0[rt], b0, acc, 0, 0, 0);
      acc = __builtin_amdgcn_mfma_f32_16x16x32_bf16(a1[rt], b1, acc, 0, 0, 0);
      float v0 = gelu_f(acc[0]);
      float v1 = gelu_f(acc[1]);
      float v2 = gelu_f(acc[2]);
      float v3 = gelu_f(acc[3]);
      if (wok){
        wsum += (v0+v1)+(v2+v3);
      } else if (tok[rt]){
        float ts = (v0+v1)+(v2+v3);
        ts += __shfl_xor(ts, 16);
        ts += __shfl_xor(ts, 32);
        if (lane < 16) unsafeAtomicAdd(&S[(size_t)gfi[rt]*1024 + (nt<<4) + lane], ts);
      } else {
        int gA = gfi[rt], gB = gla[rt];
        float sA = 0.f, sB = 0.f;
        sA += (g4[rt].x==gA)?v0:0.f; sB += (g4[rt].x==gB)?v0:0.f;
        sA += (g4[rt].y==gA)?v1:0.f; sB += (g4[rt].y==gB)?v1:0.f;
        sA += (g4[rt].z==gA)?v2:0.f; sB += (g4[rt].z==gB)?v2:0.f;
        sA += (g4[rt].w==gA)?v3:0.f; sB += (g4[rt].w==gB)?v3:0.f;
        int cb = (nt<<4) + m;
        if (g4[rt].x>=0 && g4[rt].x!=gA && g4[rt].x!=gB) unsafeAtomicAdd(&S[(size_t)g4[rt].x*1024 + cb], v0);
        if (g4[rt].y>=0 && g4[rt].y!=gA && g4[rt].y!=gB) unsafeAtomicAdd(&S[(size_t)g4[rt].y*1024 + cb], v1);
        if (g4[rt].z>=0 && g4[rt].z!=gA && g4[rt].z!=gB) unsafeAtomicAdd(&S[(size_t)g4[rt].z*1024 + cb], v2);
        if (g4[rt].w>=0 && g4[rt].w!=gA && g4[rt].w!=gB) unsafeAtomicAdd(&S[(size_t)g4[rt].w*1024 + cb], v3);
        sA += __shfl_xor(sA, 16); sA += __shfl_xor(sA, 32);
        sB += __shfl_xor(sB, 16); sB += __shfl_xor(sB, 32);
        if (lane < 16){
          unsafeAtomicAdd(&S[(size_t)gA*1024 + (nt<<4) + lane], sA);
          unsafeAtomicAdd(&S[(size_t)gB*1024 + (nt<<4) + lane], sB);
        }
      }
    }
    if (wok){
      wsum += __shfl_xor(wsum, 16);
      wsum += __shfl_xor(wsum, 32);
      if (lane < 16) unsafeAtomicAdd(&S[(size_t)gW*1024 + (nt<<4) + lane], wsum);
    }
    b0 = pb0; b1 = pb1; bias = pbias;
  }
}

// ========== edge first layer: r3 structure (rt=2, prefetch), block-offset for split dispatch ==========
__global__ __launch_bounds__(256) void kedge(const float* __restrict__ ef, const int* __restrict__ perm,
    const int* __restrict__ sg, const unsigned short* __restrict__ w1eT, const float* __restrict__ b1e,
    float* __restrict__ S, int bo){
  const int lane = threadIdx.x & 63, wv = threadIdx.x >> 6;
  const int q = lane >> 4, m = lane & 15;
  const int r0 = (bo + blockIdx.x)*128 + wv*32;
  short8 a0[2];
  int4 g4[2];
  int gfi[2], gla[2]; bool tok[2];
  const short8 zz = {0,0,0,0,0,0,0,0};
#pragma unroll
  for (int rt=0; rt<2; ++rt){
    int rb = r0 + rt*16;
    int row = rb + m;
    bool valid = row < NE;
    int e = perm[valid ? row : (NE-1)];
    short8 f = zz;
    if (valid && q < 2){
      const float4* ap = (const float4*)(ef + (size_t)e*16 + q*8);
      float4 xa = ap[0], xb = ap[1];
      f[0]=(short)f2bf(xa.x); f[1]=(short)f2bf(xa.y); f[2]=(short)f2bf(xa.z); f[3]=(short)f2bf(xa.w);
      f[4]=(short)f2bf(xb.x); f[5]=(short)f2bf(xb.y); f[6]=(short)f2bf(xb.z); f[7]=(short)f2bf(xb.w);
    }
    a0[rt] = f;
    int gb = rb + q*4;
    if (gb + 3 < NE) g4[rt] = *(const int4*)(sg + gb);
    else {
      g4[rt].x = (gb   < NE) ? sg[gb  ] : -1;
      g4[rt].y = (gb+1 < NE) ? sg[gb+1] : -1;
      g4[rt].z = (gb+2 < NE) ? sg[gb+2] : -1;
      g4[rt].w = (gb+3 < NE) ? sg[gb+3] : -1;
    }
    int gA = sg[min(rb, NE-1)], gB = sg[min(rb+15, NE-1)];
    tok[rt] = (rb + 15 < NE) && (gA == gB);
    gfi[rt] = gA; gla[rt] = gB;
  }
  int gW = sg[min(r0, NE-1)];
  bool wok = (r0 + 31 < NE) && (gW == sg[min(r0+31, NE-1)]);

  const short8* bp0 = (const short8*)(w1eT + (m << 5) + (q << 3));
  short8 b0 = bp0[0];
  float bias = b1e[m];

  for (int nt=0; nt<32; ++nt){
    int ntn = (nt + 1) & 31;
    const short8* np = (const short8*)(w1eT + (((ntn<<4) + m) << 5) + (q << 3));
    short8 pb0 = np[0];
    float pbias = b1e[(ntn<<4) + m];
    float wsum = 0.0f;
#pragma unroll
    for (int rt=0; rt<2; ++rt){
      f32x4 acc = {bias, bias, bias, bias};
      acc = __builtin_amdgcn_mfma_f32_16x16x32_bf16(a0[rt], b0, acc, 0, 0, 0);
      float v0 = gelu_f(acc[0]);
      float v1 = gelu_f(acc[1]);
      float v2 = gelu_f(acc[2]);
      float v3 = gelu_f(acc[3]);
      if (wok){
        wsum += (v0+v1)+(v2+v3);
      } else if (tok[rt]){
        float ts = (v0+v1)+(v2+v3);
        ts += __shfl_xor(ts, 16);
        ts += __shfl_xor(ts, 32);
        if (lane < 16) unsafeAtomicAdd(&S[(size_t)gfi[rt]*1024 + 512 + (nt<<4) + lane], ts);
      } else {
        int gA = gfi[rt], gB = gla[rt];
        float sA = 0.f, sB = 0.f;
        sA += (g4[rt].x==gA)?v0:0.f; sB += (g4[rt].x==gB)?v0:0.f;
        sA += (g4[rt].y==gA)?v1:0.f; sB += (g4[rt].y==gB)?v1:0.f;
        sA += (g4[rt].z==gA)?v2:0.f; sB += (g4[rt].z==gB)?v2:0.f;
        sA += (g4[rt].w==gA)?v3:0.f; sB += (g4[rt].w==gB)?v3:0.f;
        int cb = (nt<<4) + m;
        if (g4[rt].x>=0 && g4[rt].x!=gA && g4[rt].x!=gB) unsafeAtomicAdd(&S[(size_t)g4[rt].x*1024 + 512 + cb], v0);
        if (g4[rt].y>=0 && g4[rt].y!=gA && g4[rt].y!=gB) unsafeAtomicAdd(&S[(size_t)g4[rt].y*1024 + 512 + cb], v1);
        if (g4[rt].z>=0 && g4[rt].z!=gA && g4[rt].z!=gB) unsafeAtomicAdd(&S[(size_t)g4[rt].z*1024 + 512 + cb], v2);
        if (g4[rt].w>=0 && g4[rt].w!=gA && g4[rt].w!=gB) unsafeAtomicAdd(&S[(size_t)g4[rt].w*1024 + 512 + cb], v3);
        sA += __shfl_xor(sA, 16); sA += __shfl_xor(sA, 32);
        sB += __shfl_xor(sB, 16); sB += __shfl_xor(sB, 32);
        if (lane < 16){
          unsafeAtomicAdd(&S[(size_t)gA*1024 + 512 + (nt<<4) + lane], sA);
          unsafeAtomicAdd(&S[(size_t)gB*1024 + 512 + (nt<<4) + lane], sB);
        }
      }
    }
    if (wok){
      wsum += __shfl_xor(wsum, 16);
      wsum += __shfl_xor(wsum, 32);
      if (lane < 16) unsafeAtomicAdd(&S[(size_t)gW*1024 + 512 + (nt<<4) + lane], wsum);
    }
    b0 = pb0; bias = pbias;
  }
}

// ========== bf16 split (hi+lo) MFMA GEMM, 64x64 tile, fused epilogue ==========
// out[r][c] (512 cols) = acc + pre[r][c]        (pre != null)
//                      = gelu((acc+bias[c])*gam[c]*rs + bet[c])   (else)
__global__ __launch_bounds__(256) void kgemm_bf(const float* __restrict__ A, int lda, int nkc,
    const float* __restrict__ B0, const float* __restrict__ B1, float* __restrict__ out,
    const float* __restrict__ pre, const float* __restrict__ bias,
    const float* __restrict__ gam, const float* __restrict__ bet){
  __shared__ short Ah[64*40], Al[64*40], Bh[64*40], Bl[64*40];
  const int t = threadIdx.x;
  const int lane = t & 63, w = t >> 6;
  const int q = lane >> 4, m = lane & 15;
  const int c0 = blockIdx.x*64, r0 = blockIdx.y*64;
  f32x4 acc[4] = {{0.f,0.f,0.f,0.f},{0.f,0.f,0.f,0.f},{0.f,0.f,0.f,0.f},{0.f,0.f,0.f,0.f}};
  const int sa_row = t >> 2, sa_kg = t & 3;    // A: 64 rows x 4 k-octets
  const int sb_k = t >> 3, sb_ng = t & 7;      // B: 32 k x 8 col-octets
  for (int kc = 0; kc < nkc; ++kc){
    const int k0 = kc*32;
    {  // stage A 64x32 -> hi/lo
      const float* ap = A + (size_t)(r0 + sa_row)*lda + k0 + sa_kg*8;
      float4 x = *(const float4*)ap, y = *(const float4*)(ap + 4);
      float v[8] = {x.x,x.y,x.z,x.w,y.x,y.y,y.z,y.w};
      short8 hv, lv;
#pragma unroll
      for (int j=0;j<8;++j){
        unsigned short h = f2bf(v[j]);
        hv[j] = (short)h;
        lv[j] = (short)f2bf(v[j] - bf2f(h));
      }
      *(short8*)&Ah[sa_row*40 + sa_kg*8] = hv;
      *(short8*)&Al[sa_row*40 + sa_kg*8] = lv;
    }
    {  // stage B 32x64 -> transposed hi/lo [col][k]
      int kk = k0 + sb_k;
      const float* bp = ((kk < HH) ? (B0 + (size_t)kk*HH) : (B1 + (size_t)(kk-HH)*HH)) + c0 + sb_ng*8;
      float4 x = *(const float4*)bp, y = *(const float4*)(bp + 4);
      float v[8] = {x.x,x.y,x.z,x.w,y.x,y.y,y.z,y.w};
#pragma unroll
      for (int j=0;j<8;++j){
        unsigned short h = f2bf(v[j]);
        int col = sb_ng*8 + j;
        Bh[col*40 + sb_k] = (short)h;
        Bl[col*40 + sb_k] = (short)f2bf(v[j] - bf2f(h));
      }
    }
    __syncthreads();
    short8 ah = *(const short8*)&Ah[(w*16 + m)*40 + q*8];
    short8 al = *(const short8*)&Al[(w*16 + m)*40 + q*8];
#pragma unroll
    for (int cf=0; cf<4; ++cf){
      short8 bh = *(const short8*)&Bh[(cf*16 + m)*40 + q*8];
      short8 bl = *(const short8*)&Bl[(cf*16 + m)*40 + q*8];
      acc[cf] = __builtin_amdgcn_mfma_f32_16x16x32_bf16(ah, bh, acc[cf], 0, 0, 0);
      acc[cf] = __builtin_amdgcn_mfma_f32_16x16x32_bf16(ah, bl, acc[cf], 0, 0, 0);
      acc[cf] = __builtin_amdgcn_mfma_f32_16x16x32_bf16(al, bh, acc[cf], 0, 0, 0);
    }
    __syncthreads();
  }
  const float rs = 0.99999500003750f;
#pragma unroll
  for (int cf=0; cf<4; ++cf){
    int c = c0 + cf*16 + m;
    float sc = 0.f, bi = 0.f, be = 0.f;
    if (!pre){ sc = gam[c]*rs; bi = bias[c]; be = bet[c]; }
#pragma unroll
    for (int i=0;i<4;++i){
      int r = r0 + w*16 + q*4 + i;
      float v = acc[cf][i];
      if (pre) v += pre[(size_t)r*HH + c];
      else v = gelu_f((v + bi)*sc + be);
      out[(size_t)r*HH + c] = v;
    }
  }
}

// ========== final 512 -> 2 linear (activation already applied by G3) ==========
__global__ __launch_bounds__(256) void kfinal(const float* __restrict__ x2, const float* __restrict__ w3,
    const float* __restrict__ b3, float* __restrict__ out){
  const int lane = threadIdx.x & 63, wv = threadIdx.x >> 6;
  const int r = blockIdx.x*4 + wv;
  float a0 = 0.f, a1 = 0.f;
#pragma unroll
  for (int tt=0; tt<8; ++tt){
    int k = lane + tt*64;
    float x = x2[(size_t)r*HH + k];
    a0 = __builtin_fmaf(x, w3[2*k], a0);
    a1 = __builtin_fmaf(x, w3[2*k+1], a1);
  }
#pragma unroll
  for (int d=1; d<64; d<<=1){ a0 += __shfl_xor(a0, d); a1 += __shfl_xor(a1, d); }
  if (lane == 0){ out[r*2] = a0 + b3[0]; out[r*2+1] = a1 + b3[1]; }
}

extern "C" void kernel_launch(void* const* d_in, const int* in_sizes, int n_in,
                              void* d_out, int out_size, void* d_ws, size_t ws_size,
                              hipStream_t stream) {
  const float* nf    = (const float*)d_in[0];
  const float* ef    = (const float*)d_in[1];
  const float* gf    = (const float*)d_in[2];
  const float* dp    = (const float*)d_in[3];
  const int*   ny    = (const int*)d_in[4];
  const int*   bidx  = (const int*)d_in[5];
  const int*   eidx  = (const int*)d_in[6];
  const float* nfw1  = (const float*)d_in[7];
  const float* nfb1  = (const float*)d_in[8];
  const float* nfg1  = (const float*)d_in[9];
  const float* nfbe1 = (const float*)d_in[10];
  const float* w2n   = (const float*)d_in[11];
  const float* b2n   = (const float*)d_in[12];
  const float* efw1  = (const float*)d_in[13];
  const float* efb1  = (const float*)d_in[14];
  const float* efg1  = (const float*)d_in[15];
  const float* efbe1 = (const float*)d_in[16];
  const float* w2e   = (const float*)d_in[17];
  const float* b2e   = (const float*)d_in[18];
  const float* ow1   = (const float*)d_in[19];
  const float* ob1   = (const float*)d_in[20];
  const float* og1   = (const float*)d_in[21];
  const float* obe1  = (const float*)d_in[22];
  const float* ow2   = (const float*)d_in[23];
  const float* ob2   = (const float*)d_in[24];
  const float* og2   = (const float*)d_in[25];
  const float* obe2  = (const float*)d_in[26];
  const float* ow3   = (const float*)d_in[27];
  const float* ob3   = (const float*)d_in[28];

  float* S    = (float*)d_ws;                 // 1024 x 1024 (node cols 0-511, edge cols 512-1023)
  int* cnte   = (int*)(S + NG*1024);          // 1024
  int* cursor = cnte + NG;                    // 1024
  int* nstart = cursor + NG;                  // 1025
  int* eg     = nstart + NG + 1;              // NE
  int* perm   = eg + NE;                      // NE
  int* sg     = perm + NE;                    // NE
  unsigned short* w1nT = (unsigned short*)(sg + NE);  // 512*64
  unsigned short* w1eT = w1nT + HH*64;                // 512*32
  float* b1n  = (float*)(w1eT + HH*32);       // 512
  float* b1e  = b1n + HH;                     // 512
  float* gh   = b1e + HH;                     // 1024*512
  float* xg2  = gh + NG*HH;                   // 1024*512
  float* x2f  = xg2 + NG*HH;                  // 1024*512

  hipMemsetAsync(d_ws, 0, (size_t)NG*1024*sizeof(float) + NG*sizeof(int), stream);

  kpre<<<196 + 782 + 256, 256, 0, stream>>>(nfw1, nfb1, nfg1, nfbe1, efw1, efb1, efg1, efbe1,
                                            w1nT, w1eT, b1n, b1e, bidx, nstart, eidx, eg, cnte);
  kscan_init<<<129, 1024, 0, stream>>>(cnte, cursor, gf, nstart, b2n, b2e, gh);
  kscatter<<<128, 1024, 0, stream>>>(eg, cursor, perm, sg);
  knode<<<(NN+127)/128, 256, 0, stream>>>(nf, dp, ny, bidx, w1nT, b1n, S);
  // kedge split into thirds so the profile's top-5 exposes the true #2/#3 kernels
  kedge<<<1563, 256, 0, stream>>>(ef, perm, sg, w1eT, b1e, S, 0);
  kedge<<<1563, 256, 0, stream>>>(ef, perm, sg, w1eT, b1e, S, 1563);
  kedge<<<1562, 256, 0, stream>>>(ef, perm, sg, w1eT, b1e, S, 3126);
  // G1: gh = S @ [w2n;w2e] + gh_pre   (K=1024, in-place pre)
  kgemm_bf<<<dim3(8,16), 256, 0, stream>>>(S, 1024, 32, w2n, w2e, gh, gh, nullptr, nullptr, nullptr);
  // G2: xg2 = gelu(bn(gh @ ow1 + ob1))
  kgemm_bf<<<dim3(8,16), 256, 0, stream>>>(gh, 512, 16, ow1, ow1, xg2, nullptr, ob1, og1, obe1);
  // G3: x2f = gelu(bn(xg2 @ ow2 + ob2))
  kgemm_bf<<<dim3(8,16), 256, 0, stream>>>(xg2, 512, 16, ow2, ow2, x2f, nullptr, ob2, og2, obe2);
  kfinal<<<NG/4, 256, 0, stream>>>(x2f, ow3, ob3, (float*)d_out);
}

// Round 6
// 420.478 us; speedup vs baseline: 1.3391x; 1.2873x over previous
//
#include <hip/hip_runtime.h>

#define NN 200000
#define NE 600000
#define NG 1024
#define HH 512

typedef short short8 __attribute__((ext_vector_type(8)));
typedef float f32x4 __attribute__((ext_vector_type(4)));

__device__ __forceinline__ unsigned short f2bf(float f){
  unsigned u = __float_as_uint(f);
  u += 0x7fffu + ((u >> 16) & 1u);
  return (unsigned short)(u >> 16);
}
__device__ __forceinline__ float bf2f(unsigned short h){
  return __uint_as_float(((unsigned)h) << 16);
}

// gelu(x) = x * sigmoid(1.5957691216*x + 0.07135481627*x^3)  (tanh-form GELU)
__device__ __forceinline__ float gelu_f(float x){
  float p = __builtin_fmaf(x*x, -0.10294325f, -2.3022085f);
  float e = __builtin_amdgcn_exp2f(x * p);
  return x * __builtin_amdgcn_rcpf(1.0f + e);
}

// ========== merged: kprep (196 blk) + kbound (782 blk) + khist_edge (256 blk) ==========
__global__ __launch_bounds__(256) void kpre(
    const float* __restrict__ nfw1, const float* __restrict__ nfb1,
    const float* __restrict__ nfg1, const float* __restrict__ nfbe1,
    const float* __restrict__ efw1, const float* __restrict__ efb1,
    const float* __restrict__ efg1, const float* __restrict__ efbe1,
    unsigned short* __restrict__ w1nT, unsigned short* __restrict__ w1eT,
    float* __restrict__ b1n, float* __restrict__ b1e,
    const int* __restrict__ bidx, int* __restrict__ nstart,
    const int* __restrict__ eidx, int* __restrict__ eg, int* __restrict__ cnte){
  __shared__ int h[NG];
  const float rs = 0.99999500003750f;   // 1/sqrt(1+1e-5)
  int b = blockIdx.x, t = threadIdx.x;
  if (b < 196){
    int tid = b*256 + t;
    if (tid < 512*64){
      int c = tid >> 6, k = tid & 63;
      float w = (k < 41) ? nfw1[k*HH + c] * nfg1[c] * rs : 0.0f;
      w1nT[tid] = f2bf(w);
    } else if (tid < 512*96){
      int u = tid - 512*64; int c = u >> 5, k = u & 31;
      float w = (k < 16) ? efw1[k*HH + c] * efg1[c] * rs : 0.0f;
      w1eT[u] = f2bf(w);
    } else if (tid < 512*96 + 512){
      int c = tid - 512*96;
      b1n[c] = nfb1[c]*nfg1[c]*rs + nfbe1[c];
    } else if (tid < 512*96 + 1024){
      int c = tid - (512*96 + 512);
      b1e[c] = efb1[c]*efg1[c]*rs + efbe1[c];
    }
  } else if (b < 196 + 782){
    int i = (b-196)*256 + t;
    if (i < NN){
      int g0 = bidx[i];
      int g1 = (i+1 < NN) ? bidx[i+1] : NG;
      for (int g = g0+1; g <= g1; ++g) nstart[g] = i+1;
      if (i == 0) for (int g = 0; g <= g0; ++g) nstart[g] = 0;
    }
  } else {
    int hb = b - (196 + 782);             // 0..255
    for (int u = t; u < NG; u += 256) h[u] = 0;
    __syncthreads();
    for (int e = hb*256 + t; e < NE; e += 256*256){
      int g = bidx[eidx[e]];
      eg[e] = g;
      atomicAdd(&h[g], 1);
    }
    __syncthreads();
    for (int u = t; u < NG; u += 256){ int c = h[u]; if (c) atomicAdd(&cnte[u], c); }
  }
}

// ========== merged: kscan (block 0, also emits estart) + gh-init (blocks 1..128) ==========
__global__ __launch_bounds__(1024) void kscan_init(const int* __restrict__ cnte, int* __restrict__ cursor,
    int* __restrict__ estart,
    const float* __restrict__ gf, const int* __restrict__ nstart,
    const float* __restrict__ b2n, const float* __restrict__ b2e,
    float* __restrict__ gh){
  if (blockIdx.x == 0){
    __shared__ int s[NG];
    int t = threadIdx.x;
    int v = cnte[t]; s[t] = v; __syncthreads();
    for (int d = 1; d < NG; d <<= 1){
      int x = (t >= d) ? s[t-d] : 0;
      __syncthreads();
      s[t] += x;
      __syncthreads();
    }
    cursor[t] = s[t] - v;
    estart[t] = s[t] - v;
    if (t == NG-1) estart[NG] = s[t];   // == NE
  } else {
    int i = (blockIdx.x - 1)*1024 + threadIdx.x;   // float4 index over 1024*512/4
    int f = i*4;
    int r = f >> 9, c = f & 511;
    float cn = (float)(nstart[r+1] - nstart[r]);
    float ce = (float)cnte[r];
    float4 gv = *(const float4*)&gf[f];
    float4 bn4 = *(const float4*)&b2n[c];
    float4 be4 = *(const float4*)&b2e[c];
    float4 o;
    o.x = gv.x + cn*bn4.x + ce*be4.x;
    o.y = gv.y + cn*bn4.y + ce*be4.y;
    o.z = gv.z + cn*bn4.z + ce*be4.z;
    o.w = gv.w + cn*bn4.w + ce*be4.w;
    *(float4*)&gh[f] = o;
  }
}

// ========== counting-sort scatter (perm only) ==========
__global__ __launch_bounds__(1024) void kscatter(const int* __restrict__ eg, int* __restrict__ cursor,
                                                 int* __restrict__ perm){
  __shared__ int h[NG], base[NG];
  const int per = (NE + gridDim.x - 1) / gridDim.x;
  const int lo = blockIdx.x * per, hi = min(lo + per, NE);
  for (int t = threadIdx.x; t < NG; t += 1024) h[t] = 0;
  __syncthreads();
  for (int e = lo + threadIdx.x; e < hi; e += 1024) atomicAdd(&h[eg[e]], 1);
  __syncthreads();
  for (int t = threadIdx.x; t < NG; t += 1024){
    int c = h[t];
    base[t] = c ? atomicAdd(&cursor[t], c) : 0;
    h[t] = 0;
  }
  __syncthreads();
  for (int e = lo + threadIdx.x; e < hi; e += 1024){
    int g = eg[e];
    int p = base[g] + atomicAdd(&h[g], 1);
    perm[p] = e;
  }
}

// ========== fused first layers: per-(graph, col-range) blocks, B resident, no atomics ==========
// blocks 0..2047:    edge — g = bid>>1, cols = (bid&1)*256 + wave*64  (4 nt tiles)
// blocks 2048..6143: node — g = (bid-2048)>>2, cols = ((bid-2048)&3)*128 + wave*32 (2 nt tiles)
__global__ __launch_bounds__(256) void kmain(
    const float* __restrict__ nf, const float* __restrict__ dp, const int* __restrict__ ny,
    const int* __restrict__ nstart, const float* __restrict__ ef, const int* __restrict__ perm,
    const int* __restrict__ estart, const unsigned short* __restrict__ w1nT,
    const unsigned short* __restrict__ w1eT, const float* __restrict__ b1n,
    const float* __restrict__ b1e, float* __restrict__ S){
  const int t = threadIdx.x;
  const int lane = t & 63, w = t >> 6;
  const int q = lane >> 4, m = lane & 15;
  const short8 zz = {0,0,0,0,0,0,0,0};
  if (blockIdx.x < 2048){
    // ---------------- EDGE ----------------
    const int g = blockIdx.x >> 1;
    const int c0 = ((blockIdx.x & 1) << 8) + (w << 6);
    short8 bfr[4]; float bias[4]; float colacc[4] = {0.f,0.f,0.f,0.f};
#pragma unroll
    for (int nt=0; nt<4; ++nt){
      int c = c0 + (nt<<4) + m;
      bfr[nt] = *(const short8*)(w1eT + (c << 5) + (q << 3));
      bias[nt] = b1e[c];
    }
    const int s0 = estart[g], s1 = estart[g+1];
    const int nfull = (s1 - s0) >> 4;
    int rb = s0;
    for (int ch=0; ch<nfull; ++ch, rb += 16){
      int e = perm[rb + m];
      short8 f = zz;
      if (q < 2){
        const float4* ap = (const float4*)(ef + (size_t)e*16 + (q<<3));
        float4 xa = ap[0], xb = ap[1];
        f[0]=(short)f2bf(xa.x); f[1]=(short)f2bf(xa.y); f[2]=(short)f2bf(xa.z); f[3]=(short)f2bf(xa.w);
        f[4]=(short)f2bf(xb.x); f[5]=(short)f2bf(xb.y); f[6]=(short)f2bf(xb.z); f[7]=(short)f2bf(xb.w);
      }
#pragma unroll
      for (int nt=0; nt<4; ++nt){
        f32x4 acc = {bias[nt], bias[nt], bias[nt], bias[nt]};
        acc = __builtin_amdgcn_mfma_f32_16x16x32_bf16(f, bfr[nt], acc, 0, 0, 0);
        colacc[nt] += (gelu_f(acc[0]) + gelu_f(acc[1])) + (gelu_f(acc[2]) + gelu_f(acc[3]));
      }
    }
    if (rb < s1){
      int row = rb + m;
      int e = perm[(row < s1) ? row : s0];
      short8 f = zz;
      if (q < 2){
        const float4* ap = (const float4*)(ef + (size_t)e*16 + (q<<3));
        float4 xa = ap[0], xb = ap[1];
        f[0]=(short)f2bf(xa.x); f[1]=(short)f2bf(xa.y); f[2]=(short)f2bf(xa.z); f[3]=(short)f2bf(xa.w);
        f[4]=(short)f2bf(xb.x); f[5]=(short)f2bf(xb.y); f[6]=(short)f2bf(xb.z); f[7]=(short)f2bf(xb.w);
      }
      const int vr = s1 - rb;   // 1..15 valid rows in this chunk
#pragma unroll
      for (int nt=0; nt<4; ++nt){
        f32x4 acc = {bias[nt], bias[nt], bias[nt], bias[nt]};
        acc = __builtin_amdgcn_mfma_f32_16x16x32_bf16(f, bfr[nt], acc, 0, 0, 0);
        float v0 = (q*4+0 < vr) ? gelu_f(acc[0]) : 0.f;
        float v1 = (q*4+1 < vr) ? gelu_f(acc[1]) : 0.f;
        float v2 = (q*4+2 < vr) ? gelu_f(acc[2]) : 0.f;
        float v3 = (q*4+3 < vr) ? gelu_f(acc[3]) : 0.f;
        colacc[nt] += (v0+v1)+(v2+v3);
      }
    }
#pragma unroll
    for (int nt=0; nt<4; ++nt){
      float s = colacc[nt];
      s += __shfl_xor(s, 16); s += __shfl_xor(s, 32);
      if (lane < 16) S[(size_t)g*1024 + 512 + c0 + (nt<<4) + lane] = s;
    }
  } else {
    // ---------------- NODE ----------------
    const int b2 = blockIdx.x - 2048;
    const int g = b2 >> 2;
    const int c0 = ((b2 & 3) << 7) + (w << 5);
    short8 bf0[2], bf1[2]; float bias[2]; float colacc[2] = {0.f,0.f};
#pragma unroll
    for (int nt=0; nt<2; ++nt){
      int c = c0 + (nt<<4) + m;
      const short8* bp = (const short8*)(w1nT + (c << 6) + (q << 3));
      bf0[nt] = bp[0]; bf1[nt] = bp[4];
      bias[nt] = b1n[c];
    }
    const int s0 = nstart[g], s1 = nstart[g+1];
    const int nfull = (s1 - s0) >> 4;
    int rb = s0;
    for (int ch=0; ch<nfull; ++ch, rb += 16){
      int ar = rb + m;
      const float4* ap = (const float4*)(nf + (size_t)ar*32 + (q<<3));
      float4 xa = ap[0], xb = ap[1];
      short8 f;
      f[0]=(short)f2bf(xa.x); f[1]=(short)f2bf(xa.y); f[2]=(short)f2bf(xa.z); f[3]=(short)f2bf(xa.w);
      f[4]=(short)f2bf(xb.x); f[5]=(short)f2bf(xb.y); f[6]=(short)f2bf(xb.z); f[7]=(short)f2bf(xb.w);
      int cls = ny[ar];
      short dpb = (short)f2bf(dp[ar]);
      short8 h = zz;
      if (q == 0){
#pragma unroll
        for (int j=0;j<8;++j) h[j] = (cls==j) ? dpb : (short)0;
      } else if (q == 1 && cls == 8) h[0] = dpb;
#pragma unroll
      for (int nt=0; nt<2; ++nt){
        f32x4 acc = {bias[nt], bias[nt], bias[nt], bias[nt]};
        acc = __builtin_amdgcn_mfma_f32_16x16x32_bf16(f, bf0[nt], acc, 0, 0, 0);
        acc = __builtin_amdgcn_mfma_f32_16x16x32_bf16(h, bf1[nt], acc, 0, 0, 0);
        colacc[nt] += (gelu_f(acc[0]) + gelu_f(acc[1])) + (gelu_f(acc[2]) + gelu_f(acc[3]));
      }
    }
    if (rb < s1){
      int row = rb + m;
      int ar = (row < s1) ? row : s0;
      const float4* ap = (const float4*)(nf + (size_t)ar*32 + (q<<3));
      float4 xa = ap[0], xb = ap[1];
      short8 f;
      f[0]=(short)f2bf(xa.x); f[1]=(short)f2bf(xa.y); f[2]=(short)f2bf(xa.z); f[3]=(short)f2bf(xa.w);
      f[4]=(short)f2bf(xb.x); f[5]=(short)f2bf(xb.y); f[6]=(short)f2bf(xb.z); f[7]=(short)f2bf(xb.w);
      int cls = ny[ar];
      short dpb = (short)f2bf(dp[ar]);
      short8 h = zz;
      if (q == 0){
#pragma unroll
        for (int j=0;j<8;++j) h[j] = (cls==j) ? dpb : (short)0;
      } else if (q == 1 && cls == 8) h[0] = dpb;
      const int vr = s1 - rb;
#pragma unroll
      for (int nt=0; nt<2; ++nt){
        f32x4 acc = {bias[nt], bias[nt], bias[nt], bias[nt]};
        acc = __builtin_amdgcn_mfma_f32_16x16x32_bf16(f, bf0[nt], acc, 0, 0, 0);
        acc = __builtin_amdgcn_mfma_f32_16x16x32_bf16(h, bf1[nt], acc, 0, 0, 0);
        float v0 = (q*4+0 < vr) ? gelu_f(acc[0]) : 0.f;
        float v1 = (q*4+1 < vr) ? gelu_f(acc[1]) : 0.f;
        float v2 = (q*4+2 < vr) ? gelu_f(acc[2]) : 0.f;
        float v3 = (q*4+3 < vr) ? gelu_f(acc[3]) : 0.f;
        colacc[nt] += (v0+v1)+(v2+v3);
      }
    }
#pragma unroll
    for (int nt=0; nt<2; ++nt){
      float s = colacc[nt];
      s += __shfl_xor(s, 16); s += __shfl_xor(s, 32);
      if (lane < 16) S[(size_t)g*1024 + c0 + (nt<<4) + lane] = s;
    }
  }
}

// ========== bf16 split (hi+lo) MFMA GEMM, 64x64 tile, fused epilogue ==========
// out[r][c] (512 cols) = acc + pre[r][c]        (pre != null)
//                      = gelu((acc+bias[c])*gam[c]*rs + bet[c])   (else)
__global__ __launch_bounds__(256) void kgemm_bf(const float* __restrict__ A, int lda, int nkc,
    const float* __restrict__ B0, const float* __restrict__ B1, float* __restrict__ out,
    const float* __restrict__ pre, const float* __restrict__ bias,
    const float* __restrict__ gam, const float* __restrict__ bet){
  __shared__ short Ah[64*40], Al[64*40], Bh[64*40], Bl[64*40];
  const int t = threadIdx.x;
  const int lane = t & 63, w = t >> 6;
  const int q = lane >> 4, m = lane & 15;
  const int c0 = blockIdx.x*64, r0 = blockIdx.y*64;
  f32x4 acc[4] = {{0.f,0.f,0.f,0.f},{0.f,0.f,0.f,0.f},{0.f,0.f,0.f,0.f},{0.f,0.f,0.f,0.f}};
  const int sa_row = t >> 2, sa_kg = t & 3;    // A: 64 rows x 4 k-octets
  const int sb_k = t >> 3, sb_ng = t & 7;      // B: 32 k x 8 col-octets
  for (int kc = 0; kc < nkc; ++kc){
    const int k0 = kc*32;
    {  // stage A 64x32 -> hi/lo
      const float* ap = A + (size_t)(r0 + sa_row)*lda + k0 + sa_kg*8;
      float4 x = *(const float4*)ap, y = *(const float4*)(ap + 4);
      float v[8] = {x.x,x.y,x.z,x.w,y.x,y.y,y.z,y.w};
      short8 hv, lv;
#pragma unroll
      for (int j=0;j<8;++j){
        unsigned short h = f2bf(v[j]);
        hv[j] = (short)h;
        lv[j] = (short)f2bf(v[j] - bf2f(h));
      }
      *(short8*)&Ah[sa_row*40 + sa_kg*8] = hv;
      *(short8*)&Al[sa_row*40 + sa_kg*8] = lv;
    }
    {  // stage B 32x64 -> transposed hi/lo [col][k]
      int kk = k0 + sb_k;
      const float* bp = ((kk < HH) ? (B0 + (size_t)kk*HH) : (B1 + (size_t)(kk-HH)*HH)) + c0 + sb_ng*8;
      float4 x = *(const float4*)bp, y = *(const float4*)(bp + 4);
      float v[8] = {x.x,x.y,x.z,x.w,y.x,y.y,y.z,y.w};
#pragma unroll
      for (int j=0;j<8;++j){
        unsigned short h = f2bf(v[j]);
        int col = sb_ng*8 + j;
        Bh[col*40 + sb_k] = (short)h;
        Bl[col*40 + sb_k] = (short)f2bf(v[j] - bf2f(h));
      }
    }
    __syncthreads();
    short8 ah = *(const short8*)&Ah[(w*16 + m)*40 + q*8];
    short8 al = *(const short8*)&Al[(w*16 + m)*40 + q*8];
#pragma unroll
    for (int cf=0; cf<4; ++cf){
      short8 bh = *(const short8*)&Bh[(cf*16 + m)*40 + q*8];
      short8 bl = *(const short8*)&Bl[(cf*16 + m)*40 + q*8];
      acc[cf] = __builtin_amdgcn_mfma_f32_16x16x32_bf16(ah, bh, acc[cf], 0, 0, 0);
      acc[cf] = __builtin_amdgcn_mfma_f32_16x16x32_bf16(ah, bl, acc[cf], 0, 0, 0);
      acc[cf] = __builtin_amdgcn_mfma_f32_16x16x32_bf16(al, bh, acc[cf], 0, 0, 0);
    }
    __syncthreads();
  }
  const float rs = 0.99999500003750f;
#pragma unroll
  for (int cf=0; cf<4; ++cf){
    int c = c0 + cf*16 + m;
    float sc = 0.f, bi = 0.f, be = 0.f;
    if (!pre){ sc = gam[c]*rs; bi = bias[c]; be = bet[c]; }
#pragma unroll
    for (int i=0;i<4;++i){
      int r = r0 + w*16 + q*4 + i;
      float v = acc[cf][i];
      if (pre) v += pre[(size_t)r*HH + c];
      else v = gelu_f((v + bi)*sc + be);
      out[(size_t)r*HH + c] = v;
    }
  }
}

// ========== final 512 -> 2 linear (activation already applied by G3) ==========
__global__ __launch_bounds__(256) void kfinal(const float* __restrict__ x2, const float* __restrict__ w3,
    const float* __restrict__ b3, float* __restrict__ out){
  const int lane = threadIdx.x & 63, wv = threadIdx.x >> 6;
  const int r = blockIdx.x*4 + wv;
  float a0 = 0.f, a1 = 0.f;
#pragma unroll
  for (int tt=0; tt<8; ++tt){
    int k = lane + tt*64;
    float x = x2[(size_t)r*HH + k];
    a0 = __builtin_fmaf(x, w3[2*k], a0);
    a1 = __builtin_fmaf(x, w3[2*k+1], a1);
  }
#pragma unroll
  for (int d=1; d<64; d<<=1){ a0 += __shfl_xor(a0, d); a1 += __shfl_xor(a1, d); }
  if (lane == 0){ out[r*2] = a0 + b3[0]; out[r*2+1] = a1 + b3[1]; }
}

extern "C" void kernel_launch(void* const* d_in, const int* in_sizes, int n_in,
                              void* d_out, int out_size, void* d_ws, size_t ws_size,
                              hipStream_t stream) {
  const float* nf    = (const float*)d_in[0];
  const float* ef    = (const float*)d_in[1];
  const float* gf    = (const float*)d_in[2];
  const float* dp    = (const float*)d_in[3];
  const int*   ny    = (const int*)d_in[4];
  const int*   bidx  = (const int*)d_in[5];
  const int*   eidx  = (const int*)d_in[6];
  const float* nfw1  = (const float*)d_in[7];
  const float* nfb1  = (const float*)d_in[8];
  const float* nfg1  = (const float*)d_in[9];
  const float* nfbe1 = (const float*)d_in[10];
  const float* w2n   = (const float*)d_in[11];
  const float* b2n   = (const float*)d_in[12];
  const float* efw1  = (const float*)d_in[13];
  const float* efb1  = (const float*)d_in[14];
  const float* efg1  = (const float*)d_in[15];
  const float* efbe1 = (const float*)d_in[16];
  const float* w2e   = (const float*)d_in[17];
  const float* b2e   = (const float*)d_in[18];
  const float* ow1   = (const float*)d_in[19];
  const float* ob1   = (const float*)d_in[20];
  const float* og1   = (const float*)d_in[21];
  const float* obe1  = (const float*)d_in[22];
  const float* ow2   = (const float*)d_in[23];
  const float* ob2   = (const float*)d_in[24];
  const float* og2   = (const float*)d_in[25];
  const float* obe2  = (const float*)d_in[26];
  const float* ow3   = (const float*)d_in[27];
  const float* ob3   = (const float*)d_in[28];

  float* S    = (float*)d_ws;                 // 1024 x 1024 (node cols 0-511, edge cols 512-1023)
  int* cnte   = (int*)(S + NG*1024);          // 1024
  int* cursor = cnte + NG;                    // 1024
  int* nstart = cursor + NG;                  // 1025
  int* estart = nstart + NG + 1;              // 1025
  int* eg     = estart + NG + 1;              // NE
  int* perm   = eg + NE;                      // NE
  unsigned short* w1nT = (unsigned short*)(perm + NE);  // 512*64
  unsigned short* w1eT = w1nT + HH*64;                  // 512*32
  float* b1n  = (float*)(w1eT + HH*32);       // 512
  float* b1e  = b1n + HH;                     // 512
  float* gh   = b1e + HH;                     // 1024*512
  float* xg2  = gh + NG*HH;                   // 1024*512
  float* x2f  = xg2 + NG*HH;                  // 1024*512

  hipMemsetAsync(cnte, 0, NG*sizeof(int), stream);   // only the histogram needs zeroing

  kpre<<<196 + 782 + 256, 256, 0, stream>>>(nfw1, nfb1, nfg1, nfbe1, efw1, efb1, efg1, efbe1,
                                            w1nT, w1eT, b1n, b1e, bidx, nstart, eidx, eg, cnte);
  kscan_init<<<129, 1024, 0, stream>>>(cnte, cursor, estart, gf, nstart, b2n, b2e, gh);
  kscatter<<<128, 1024, 0, stream>>>(eg, cursor, perm);
  kmain<<<6144, 256, 0, stream>>>(nf, dp, ny, nstart, ef, perm, estart,
                                  w1nT, w1eT, b1n, b1e, S);
  // G1: gh = S @ [w2n;w2e] + gh_pre   (K=1024, in-place pre)
  kgemm_bf<<<dim3(8,16), 256, 0, stream>>>(S, 1024, 32, w2n, w2e, gh, gh, nullptr, nullptr, nullptr);
  // G2: xg2 = gelu(bn(gh @ ow1 + ob1))
  kgemm_bf<<<dim3(8,16), 256, 0, stream>>>(gh, 512, 16, ow1, ow1, xg2, nullptr, ob1, og1, obe1);
  // G3: x2f = gelu(bn(xg2 @ ow2 + ob2))
  kgemm_bf<<<dim3(8,16), 256, 0, stream>>>(xg2, 512, 16, ow2, ow2, x2f, nullptr, ob2, og2, obe2);
  kfinal<<<NG/4, 256, 0, stream>>>(x2f, ow3, ob3, (float*)d_out);
}